// Round 13
// baseline (66.696 us; speedup 1.0000x reference)
//
#include <hip/hip_runtime.h>
#include <stdint.h>

// Problem constants (match reference)
#define BATCH 16
#define NN    8192
#define DD    8
#define NEXTN 4096
#define KTOT  (NN + NEXTN)

#define SPLIT 128                // spmm row-chunks (grid.y)
#define SUB   48                 // compaction subchunk rows (one wave, lanes<48)
#define NSUB  (KTOT / SUB)       // 256 subchunks; each spmm chunk = 2 subchunks
#define THREADS 512              // 8 waves/block
#define NTILES 4                 // 2048 cols per block (512 thr x float4)
// grid = 4 x 128 = 512 blocks x 8 waves = 4096 waves = 16 waves/CU (same as
// R11) but HALF the row-visits and 8 KB contiguous burst per visit.

// Workspace layout (bytes)
#define CNT_OFF  1024                      // cnt[NSUB] u32
#define LIST_OFF 4096                      // list[KTOT] u32 packed (mask<<16|row)
#define PART_OFF 65536                     // fp16 partial[SPLIT][BATCH][NN] (32 MB)

typedef _Float16 half4_t __attribute__((ext_vector_type(4)));

// ---------------------------------------------------------------------------
// K1: masks + deterministic ballot compaction, one wave per 48-row subchunk.
// Writes packed (mask<<16 | row) active-row lists and per-subchunk counts.
// dmap dtype (bool bytes / int32 / float32) detected from first 256 words.
__global__ __launch_bounds__(64) void k_masks(const void* __restrict__ dmap,
                                              const float* __restrict__ Xbuf,
                                              const float* __restrict__ Xext,
                                              uint32_t* __restrict__ list,
                                              uint32_t* __restrict__ cnt) {
    const int lane = (int)threadIdx.x;

    // wave-level dtype detection
    int f = 0, o = 0;
    {
        const uint32_t* w = (const uint32_t*)dmap;
        #pragma unroll
        for (int k = 0; k < 4; ++k) {
            const uint32_t v = w[lane * 4 + k];
            if (v == 0x3F800000u) f = 1;
            else if (v > 1u) o = 1;
        }
    }
    const int fmt = __ballot(f) ? 2 : (__ballot(o) ? 0 : 1); // 0=byte,1=i32,2=f32

    const int r = (int)blockIdx.x * SUB + lane;
    uint32_t m = 0;
    bool act = false;
    if (lane < SUB) {
        if (r < NN) {
            int dsel = 0;
            if (fmt == 0) {
                const uint8_t* p = (const uint8_t*)dmap;
                #pragma unroll
                for (int d = DD - 1; d >= 0; --d) if (p[d * NN + r]) dsel = d;
            } else if (fmt == 1) {
                const int* p = (const int*)dmap;
                #pragma unroll
                for (int d = DD - 1; d >= 0; --d) if (p[d * NN + r]) dsel = d;
            } else {
                const float* p = (const float*)dmap;
                #pragma unroll
                for (int d = DD - 1; d >= 0; --d) if (p[d * NN + r] != 0.0f) dsel = d;
            }
            const float* xb = Xbuf + (size_t)dsel * BATCH * NN + r;
            #pragma unroll
            for (int b = 0; b < BATCH; ++b)
                m |= (xb[(size_t)b * NN] != 0.0f ? 1u : 0u) << b;
        } else {
            const int k = r - NN;
            #pragma unroll
            for (int b = 0; b < BATCH; ++b)
                m |= (Xext[(size_t)b * NEXTN + k] != 0.0f ? 1u : 0u) << b;
        }
        act = (m != 0u);
    }
    const uint64_t bal = __ballot(act);
    const uint32_t pos = (uint32_t)__popcll(bal & ((1ull << lane) - 1ull));
    if (act) list[(size_t)blockIdx.x * SUB + pos] = (m << 16) | (uint32_t)r;
    if (lane == 0) cnt[blockIdx.x] = (uint32_t)__popcll(bal);
}

// ---------------------------------------------------------------------------
// K2: one-visit sparse accumulation. Block = (column tile x, row chunk z).
// All control state is wave-uniform -> s_load (SMEM pipe) + SALU; fb is an
// s_cselect between float literals. Inner loop: s_load -> SALU -> one
// dwordx4 vector load (8 KB/block burst) -> 64 v_fmac with SGPR multiplier.
// No LDS, no barrier. Partial stores nontemporal.
__global__ __launch_bounds__(THREADS) void k_spmm(const float* __restrict__ Wint,
                                                  const float* __restrict__ Wext,
                                                  const uint32_t* __restrict__ list,
                                                  const uint32_t* __restrict__ cnt,
                                                  _Float16* __restrict__ partial) {
    const int j0 = (int)blockIdx.x * (THREADS * 4) + (int)threadIdx.x * 4;
    const int z  = (int)blockIdx.y;

    float4 acc[BATCH];
    #pragma unroll
    for (int b = 0; b < BATCH; ++b) acc[b] = make_float4(0.f, 0.f, 0.f, 0.f);

    #pragma unroll
    for (int s = 0; s < 2; ++s) {
        const int sub = 2 * z + s;
        const uint32_t n = cnt[sub];                 // uniform -> s_load
        const uint32_t* lp = list + (size_t)sub * SUB;
        #pragma unroll 8
        for (uint32_t k = 0; k < n; ++k) {
            const uint32_t rm = lp[k];               // uniform -> s_load
            const int      r  = (int)(rm & 0xFFFFu);
            const uint32_t mm = rm >> 16;
            const float* wp = (r < NN) ? (Wint + (size_t)r * NN + j0)
                                       : (Wext + (size_t)(r - NN) * NN + j0);
            const float4 w = *(const float4*)wp;
            #pragma unroll
            for (int b = 0; b < BATCH; ++b) {
                const float fb = ((mm >> b) & 1u) ? 1.0f : 0.0f;  // s_cselect
                acc[b].x = fmaf(w.x, fb, acc[b].x);
                acc[b].y = fmaf(w.y, fb, acc[b].y);
                acc[b].z = fmaf(w.z, fb, acc[b].z);
                acc[b].w = fmaf(w.w, fb, acc[b].w);
            }
        }
    }

    _Float16* outp = partial + (size_t)z * BATCH * NN + j0;
    #pragma unroll
    for (int b = 0; b < BATCH; ++b) {
        half4_t hv;
        hv.x = (_Float16)acc[b].x;
        hv.y = (_Float16)acc[b].y;
        hv.z = (_Float16)acc[b].z;
        hv.w = (_Float16)acc[b].w;
        __builtin_nontemporal_store(hv, (half4_t*)(outp + (size_t)b * NN));
    }
}

// ---------------------------------------------------------------------------
// K3: reduce SPLIT fp16 partials (fixed order -> deterministic) + ALIF
// pointwise. Nontemporal partial reads (single-use; keep weights in L3).
__global__ __launch_bounds__(256) void k_final(const float* __restrict__ V,
                                               const float* __restrict__ a,
                                               const _Float16* __restrict__ partial,
                                               float* __restrict__ out) {
    const int idx = blockIdx.x * 256 + (int)threadIdx.x;
    if (idx >= BATCH * NN) return;

    float cur = 0.0f;
    #pragma unroll 16
    for (int z = 0; z < SPLIT; ++z)
        cur += (float)__builtin_nontemporal_load(partial + (size_t)z * BATCH * NN + idx);

    const float v  = V[idx];
    const float ai = a[idx];
    const float u  = v - (1.0f + 1.8f * ai);
    const float X  = (u >= 0.0f) ? 1.0f : 0.0f;
    out[idx]                  = X;
    out[BATCH * NN + idx]     = 0.95f * v * (1.0f - X) + cur;
    out[2 * BATCH * NN + idx] = 0.99f * ai + X;
}

// ---------------------------------------------------------------------------
extern "C" void kernel_launch(void* const* d_in, const int* in_sizes, int n_in,
                              void* d_out, int out_size, void* d_ws, size_t ws_size,
                              hipStream_t stream) {
    const float* V    = (const float*)d_in[0];
    const float* a    = (const float*)d_in[1];
    const float* Xbuf = (const float*)d_in[2];
    const void*  dmap = d_in[3];
    const float* Wint = (const float*)d_in[4];
    const float* Xext = (const float*)d_in[5];
    const float* Wext = (const float*)d_in[6];
    float* out = (float*)d_out;

    uint8_t* ws = (uint8_t*)d_ws;
    uint32_t* cnt     = (uint32_t*)(ws + CNT_OFF);
    uint32_t* list    = (uint32_t*)(ws + LIST_OFF);
    _Float16* partial = (_Float16*)(ws + PART_OFF);

    hipLaunchKernelGGL(k_masks, dim3(NSUB), dim3(64), 0, stream,
                       dmap, Xbuf, Xext, list, cnt);
    hipLaunchKernelGGL(k_spmm, dim3(NTILES, SPLIT), dim3(THREADS), 0, stream,
                       Wint, Wext, list, cnt, partial);
    hipLaunchKernelGGL(k_final, dim3((BATCH * NN + 255) / 256), dim3(256), 0, stream,
                       V, a, partial, out);
}

// Round 14
// 61.559 us; speedup vs baseline: 1.0834x; 1.0834x over previous
//
#include <hip/hip_runtime.h>
#include <stdint.h>

// Problem constants (match reference)
#define BATCH 16
#define NN    8192
#define DD    8
#define NEXTN 4096
#define KTOT  (NN + NEXTN)

#define SPLIT 64                 // spmm row-chunks (grid.y) -> 512 blocks, 8 waves/CU
#define SUB   48                 // compaction subchunk rows (one wave, lanes<48)
#define NSUB  (KTOT / SUB)       // 256 subchunks; each spmm chunk = 4 subchunks
#define NTILES 8                 // 1024 cols per block (256 thr x float4)
// A/B vs R11: identical scalarized loop, SPLIT 128->64. Partial traffic
// halves (32->16 MB each way); tests whether s_load-prefetched ILP can
// substitute for wave concurrency at 8 waves/CU (R10's failure predates
// the scalarization; its per-row chain was vector-latency-serialized).

// Workspace layout (bytes)
#define CNT_OFF  1024                      // cnt[NSUB] u32
#define LIST_OFF 4096                      // list[KTOT] u32 packed (mask<<16|row)
#define PART_OFF 65536                     // fp16 partial[SPLIT][BATCH][NN] (16 MB)

typedef _Float16 half4_t __attribute__((ext_vector_type(4)));

// ---------------------------------------------------------------------------
// K1: masks + deterministic ballot compaction, one wave per 48-row subchunk.
// Writes packed (mask<<16 | row) active-row lists and per-subchunk counts.
// dmap dtype (bool bytes / int32 / float32) detected from first 256 words.
__global__ __launch_bounds__(64) void k_masks(const void* __restrict__ dmap,
                                              const float* __restrict__ Xbuf,
                                              const float* __restrict__ Xext,
                                              uint32_t* __restrict__ list,
                                              uint32_t* __restrict__ cnt) {
    const int lane = (int)threadIdx.x;

    // wave-level dtype detection
    int f = 0, o = 0;
    {
        const uint32_t* w = (const uint32_t*)dmap;
        #pragma unroll
        for (int k = 0; k < 4; ++k) {
            const uint32_t v = w[lane * 4 + k];
            if (v == 0x3F800000u) f = 1;
            else if (v > 1u) o = 1;
        }
    }
    const int fmt = __ballot(f) ? 2 : (__ballot(o) ? 0 : 1); // 0=byte,1=i32,2=f32

    const int r = (int)blockIdx.x * SUB + lane;
    uint32_t m = 0;
    bool act = false;
    if (lane < SUB) {
        if (r < NN) {
            int dsel = 0;
            if (fmt == 0) {
                const uint8_t* p = (const uint8_t*)dmap;
                #pragma unroll
                for (int d = DD - 1; d >= 0; --d) if (p[d * NN + r]) dsel = d;
            } else if (fmt == 1) {
                const int* p = (const int*)dmap;
                #pragma unroll
                for (int d = DD - 1; d >= 0; --d) if (p[d * NN + r]) dsel = d;
            } else {
                const float* p = (const float*)dmap;
                #pragma unroll
                for (int d = DD - 1; d >= 0; --d) if (p[d * NN + r] != 0.0f) dsel = d;
            }
            const float* xb = Xbuf + (size_t)dsel * BATCH * NN + r;
            #pragma unroll
            for (int b = 0; b < BATCH; ++b)
                m |= (xb[(size_t)b * NN] != 0.0f ? 1u : 0u) << b;
        } else {
            const int k = r - NN;
            #pragma unroll
            for (int b = 0; b < BATCH; ++b)
                m |= (Xext[(size_t)b * NEXTN + k] != 0.0f ? 1u : 0u) << b;
        }
        act = (m != 0u);
    }
    const uint64_t bal = __ballot(act);
    const uint32_t pos = (uint32_t)__popcll(bal & ((1ull << lane) - 1ull));
    if (act) list[(size_t)blockIdx.x * SUB + pos] = (m << 16) | (uint32_t)r;
    if (lane == 0) cnt[blockIdx.x] = (uint32_t)__popcll(bal);
}

// ---------------------------------------------------------------------------
// K2: one-visit sparse accumulation. Block = (column tile x, row chunk z).
// All control state is wave-uniform -> s_load (SMEM pipe) + SALU; fb is an
// s_cselect between float literals. Inner loop: s_load -> SALU -> one
// dwordx4 vector load -> 64 v_fmac with SGPR multiplier. No LDS, no barrier.
__global__ __launch_bounds__(256) void k_spmm(const float* __restrict__ Wint,
                                              const float* __restrict__ Wext,
                                              const uint32_t* __restrict__ list,
                                              const uint32_t* __restrict__ cnt,
                                              _Float16* __restrict__ partial) {
    const int j0 = (int)blockIdx.x * 1024 + (int)threadIdx.x * 4;
    const int z  = (int)blockIdx.y;

    float4 acc[BATCH];
    #pragma unroll
    for (int b = 0; b < BATCH; ++b) acc[b] = make_float4(0.f, 0.f, 0.f, 0.f);

    #pragma unroll
    for (int s = 0; s < 4; ++s) {
        const int sub = 4 * z + s;
        const uint32_t n = cnt[sub];                 // uniform -> s_load
        const uint32_t* lp = list + (size_t)sub * SUB;
        #pragma unroll 8
        for (uint32_t k = 0; k < n; ++k) {
            const uint32_t rm = lp[k];               // uniform -> s_load
            const int      r  = (int)(rm & 0xFFFFu);
            const uint32_t mm = rm >> 16;
            const float* wp = (r < NN) ? (Wint + (size_t)r * NN + j0)
                                       : (Wext + (size_t)(r - NN) * NN + j0);
            const float4 w = *(const float4*)wp;
            #pragma unroll
            for (int b = 0; b < BATCH; ++b) {
                const float fb = ((mm >> b) & 1u) ? 1.0f : 0.0f;  // s_cselect
                acc[b].x = fmaf(w.x, fb, acc[b].x);
                acc[b].y = fmaf(w.y, fb, acc[b].y);
                acc[b].z = fmaf(w.z, fb, acc[b].z);
                acc[b].w = fmaf(w.w, fb, acc[b].w);
            }
        }
    }

    _Float16* outp = partial + (size_t)z * BATCH * NN + j0;
    #pragma unroll
    for (int b = 0; b < BATCH; ++b) {
        half4_t hv;
        hv.x = (_Float16)acc[b].x;
        hv.y = (_Float16)acc[b].y;
        hv.z = (_Float16)acc[b].z;
        hv.w = (_Float16)acc[b].w;
        __builtin_nontemporal_store(hv, (half4_t*)(outp + (size_t)b * NN));
    }
}

// ---------------------------------------------------------------------------
// K3: reduce SPLIT fp16 partials (fixed order -> deterministic) + ALIF
// pointwise. One col per thread, 512 blocks; unroll 16 for load MLP.
__global__ __launch_bounds__(256) void k_final(const float* __restrict__ V,
                                               const float* __restrict__ a,
                                               const _Float16* __restrict__ partial,
                                               float* __restrict__ out) {
    const int idx = blockIdx.x * 256 + (int)threadIdx.x;
    if (idx >= BATCH * NN) return;

    float cur = 0.0f;
    #pragma unroll 16
    for (int z = 0; z < SPLIT; ++z)
        cur += (float)partial[(size_t)z * BATCH * NN + idx];

    const float v  = V[idx];
    const float ai = a[idx];
    const float u  = v - (1.0f + 1.8f * ai);
    const float X  = (u >= 0.0f) ? 1.0f : 0.0f;
    out[idx]                  = X;
    out[BATCH * NN + idx]     = 0.95f * v * (1.0f - X) + cur;
    out[2 * BATCH * NN + idx] = 0.99f * ai + X;
}

// ---------------------------------------------------------------------------
extern "C" void kernel_launch(void* const* d_in, const int* in_sizes, int n_in,
                              void* d_out, int out_size, void* d_ws, size_t ws_size,
                              hipStream_t stream) {
    const float* V    = (const float*)d_in[0];
    const float* a    = (const float*)d_in[1];
    const float* Xbuf = (const float*)d_in[2];
    const void*  dmap = d_in[3];
    const float* Wint = (const float*)d_in[4];
    const float* Xext = (const float*)d_in[5];
    const float* Wext = (const float*)d_in[6];
    float* out = (float*)d_out;

    uint8_t* ws = (uint8_t*)d_ws;
    uint32_t* cnt     = (uint32_t*)(ws + CNT_OFF);
    uint32_t* list    = (uint32_t*)(ws + LIST_OFF);
    _Float16* partial = (_Float16*)(ws + PART_OFF);

    hipLaunchKernelGGL(k_masks, dim3(NSUB), dim3(64), 0, stream,
                       dmap, Xbuf, Xext, list, cnt);
    hipLaunchKernelGGL(k_spmm, dim3(NTILES, SPLIT), dim3(256), 0, stream,
                       Wint, Wext, list, cnt, partial);
    hipLaunchKernelGGL(k_final, dim3((BATCH * NN + 255) / 256), dim3(256), 0, stream,
                       V, a, partial, out);
}